// Round 10
// baseline (4295.833 us; speedup 1.0000x reference)
//
#include <hip/hip_runtime.h>

#define DEVI __device__ __forceinline__

typedef __attribute__((ext_vector_type(4))) float f4;
typedef long long i64t;

DEVI unsigned char f2fp8(float x) {
  int p = __builtin_amdgcn_cvt_pk_fp8_f32(x, x, 0, false);
  return (unsigned char)(p & 0xff);
}
DEVI float fp82f(unsigned char b) {
  return __builtin_amdgcn_cvt_f32_fp8((int)b, 0);
}
DEVI float sigmoidf_(float x) { return 1.f / (1.f + __expf(-x)); }
DEVI float tanhf_(float x) {
  float ax = fabsf(x);
  float e = __expf(-2.f * ax);
  float t = (1.f - e) / (1.f + e);
  return x < 0.f ? -t : t;
}

#define GLDS16(g, l) __builtin_amdgcn_global_load_lds( \
    (const __attribute__((address_space(1))) void*)(g), \
    (__attribute__((address_space(3))) void*)(l), 16, 0, 0)

// All GEMM operands are fp8 e4m3 scaled by 64 (raw values ~N(0,0.02) are
// subnormal in e4m3; x64 centers them in the normal range). acc = 4096*z;
// epilogue multiplies by 1/4096.
#define SCALE_UP 64.0f
#define SCALE_DN (1.0f / 4096.0f)

// ---------------- conversion kernels ----------------

__global__ void k_conv_emb(const float* __restrict__ emb, unsigned char* __restrict__ ep) {
  int i = blockIdx.x * 256 + threadIdx.x;            // 10000 * 128
  if (i >= 10000 * 128) return;
  int r = i >> 7, c = i & 127;
  ep[i] = (c < 100) ? f2fp8(emb[r * 100 + c] * SCALE_UP) : (unsigned char)0;
}

// column permutation: original col n = gate*1024 + u  ->
// n' = (u/32)*128 + ((u%32)/16)*64 + gate*16 + (u%16)
DEVI int permn(int n) {
  int g = n >> 10, u = n & 1023;
  return (u >> 5) * 128 + ((u >> 4) & 1) * 64 + g * 16 + (u & 15);
}
// bank swizzle baked into storage, 8-BYTE granule: within each 64B k-block,
// 8B slot s of row r holds logical slot s ^ ((r>>1)&7). This gives each
// quarter-wave (16 lanes, the LDS coalescing window) all 32 banks exactly
// once on ds_read_b64. (Verified round 2: SQ_LDS_BANK_CONFLICT 6.55M -> 65K.)
DEVI int kswz(int klog, int row) {
  return (klog & ~63) | (((((klog >> 3) & 7) ^ ((row >> 1) & 7))) << 3) | (klog & 7);
}

__global__ void k_conv_w0(const float* __restrict__ W0, const float* __restrict__ U0,
                          unsigned char* __restrict__ WT) {
  int i = blockIdx.x * 256 + threadIdx.x;            // 4096 * 1152
  if (i >= 4096 * 1152) return;
  int n = i / 1152, k = i - n * 1152;
  float v;
  if (k < 100) v = W0[k * 4096 + n];
  else if (k < 128) v = 0.f;
  else v = U0[(k - 128) * 4096 + n];
  int np = permn(n);
  WT[(size_t)np * 1152 + kswz(k, np)] = f2fp8(v * SCALE_UP);
}

__global__ void k_conv_w1(const float* __restrict__ W1, const float* __restrict__ U1,
                          unsigned char* __restrict__ WT) {
  int i = blockIdx.x * 256 + threadIdx.x;            // 4096 * 2048
  if (i >= 4096 * 2048) return;
  int n = i >> 11, k = i & 2047;
  float v = (k < 1024) ? W1[k * 4096 + n] : U1[(k - 1024) * 4096 + n];
  int np = permn(n);
  WT[(size_t)np * 2048 + kswz(k, np)] = f2fp8(v * SCALE_UP);
}

// ---------------- fused LSTM phase (fp8) ------------------------------------
// Round 10: FINER BLOCKS for barrier-group independence. 64x128 tile,
// 256 threads (4 waves as 2M x 2N; each wave 32m x 64n' — identical per-wave
// code to round 9). Grid 1024 -> 4 blocks/CU (24 KB LDS each, 96 KB/CU),
// 16 waves/CU in 4 INDEPENDENT barrier groups (1 wave/block/SIMD). Rationale
// (r9 post-mortem): with 2 barrier groups the matrix pipe starves whenever
// both groups are in their post-barrier stage/ds_read phase (~50% idle,
// matching MfmaUtil 43). 4 independent groups -> P(all idle) ~ 1%.
// Counted-vmcnt rewrite rejected by arithmetic: stage is issued right after
// each barrier, so the next __syncthreads' vmcnt(0) drains loads issued a
// full half-iteration (~1200cy) earlier — already slack-covered.
// MERGED-BLOCK: every block runs L0(t) (18 kb) then L1(t-1) (32 kb) on the
// same 64 m-rows — uniform work, no placement assumptions (r5 lesson).
// Proven pieces kept: 2-phase __syncthreads schedule, K-loop unroll-2
// (compile-time LDS buffer binding), 8B-granule bank swizzle in h/WT
// storage, embp stage-time 16B XOR (kb<2 of L0, 16B-granule readback),
// fp32 c-state (bf16 r6/r7 gave no per-dispatch gain).

template<int K1, int KTOT, bool GATHER>
DEVI void lstm_phase(int m0, int n0, char* smem,
    const unsigned char* __restrict__ src1,   // embp (gathered) or h0(t-1)
    const unsigned char* __restrict__ src2,   // h prev (recurrent input)
    const int* __restrict__ idx, int t,
    const unsigned char* __restrict__ WT,     // [4096][KTOT] fp8, perm+swz
    const float* __restrict__ bias,           // [4096] original layout
    float* __restrict__ cbuf,                 // [2048][1024] fp32, in-place
    unsigned char* __restrict__ hout)         // [2048][1024] fp8 x64, swz
{
  const int tid = threadIdx.x;               // 0..255

  const int lr = tid >> 2;                 // staging row 0..63
  const int c16 = (tid & 3) * 16;          // plain 16B chunk offset
  // stage-time 16B XOR for gathered embp: dest chunk (tid&3) at LDS row lr
  // holds logical chunk (tid&3) ^ ((lr>>1)&3)
  const int csw = (((tid & 3) ^ ((tid >> 3) & 3))) * 16;

  const unsigned char* g1 = nullptr;       // gathered embp row (pre-offset)
  if (GATHER) {
    int w = idx[(m0 + lr) * 80 + t];
    g1 = src1 + (size_t)w * K1 + csw;
  }

  // hoisted staging base pointers (advance by kc only)
  const unsigned char* wbase = WT + (size_t)(n0 + lr) * KTOT + c16;
  const unsigned char* a1b = src1 + (size_t)(m0 + lr) * 1024 + c16;  // !GATHER
  const unsigned char* a2b = src2 + (size_t)(m0 + lr) * 1024 + c16 - K1;

  // two stage buffers: each 12KB = A[64][64] (4KB) + B[128][64] (8KB)
  char* const LA0 = smem;
  char* const LB0 = smem + 4096;
  char* const LA1 = smem + 12288;
  char* const LB1 = smem + 16384;

  auto stage = [&](int kb, char* la, char* lb) {
    const int kc = kb * 64;
    if (GATHER && kc < K1) {
      GLDS16(g1 + kc, la + tid * 16);
    } else {
      const unsigned char* g = (!GATHER && kc < K1) ? a1b + kc : a2b + kc;
      GLDS16(g, la + tid * 16);
    }
#pragma unroll
    for (int p = 0; p < 2; ++p)
      GLDS16(wbase + (size_t)p * 64 * KTOT + kc,
             lb + p * 4096 + tid * 16);
  };

  const int lane = tid & 63;
  const int wv = tid >> 6;    // 0..3
  const int wm = wv >> 1;     // wave m-half (0..1), 32 rows each
  const int wn = wv & 1;      // wave n-half (0..1), 64 n'-rows each
  const int cl = lane & 15;
  const int qd = lane >> 4;
  const int qh = qd >> 1, qb = qd & 1;
  // 8B-granule swizzled fragment byte-offsets (baked storage):
  // logical 8B slot for (kk,qd) = kk*4 + qd; phys = slot ^ ((cl>>1)&7)
  const int g8s = (cl >> 1) & 7;
  const int ko8_0 = ((0 + qd) ^ g8s) << 3;
  const int ko8_1 = ((4 + qd) ^ g8s) << 3;
  // 16B-granule offsets (embp-gathered A tiles only, kb<2 of layer 0)
  const int g4s = (cl >> 1) & 3;
  const int ko16_0 = ((qh ^ g4s) << 4) + qb * 8;
  const int ko16_1 = (((2 + qh) ^ g4s) << 4) + qb * 8;

  f4 acc[2][4];
  const f4 fz = {0.f, 0.f, 0.f, 0.f};
#pragma unroll
  for (int a = 0; a < 2; ++a)
#pragma unroll
    for (int b = 0; b < 4; ++b) acc[a][b] = fz;

  auto compute = [&](char* la, char* lb, int koA0, int koA1) {
#pragma unroll
    for (int kk = 0; kk < 2; ++kk) {
      const int koA = kk ? koA1 : koA0;
      const int koB = kk ? ko8_1 : ko8_0;
      i64t af[2], bfr[4];
#pragma unroll
      for (int mi = 0; mi < 2; ++mi)
        af[mi] = *(const i64t*)(la + (wm * 32 + mi * 16 + cl) * 64 + koA);
#pragma unroll
      for (int j = 0; j < 4; ++j)
        bfr[j] = *(const i64t*)(lb + (wn * 64 + j * 16 + cl) * 64 + koB);
#pragma unroll
      for (int mi = 0; mi < 2; ++mi)
#pragma unroll
        for (int j = 0; j < 4; ++j)
          acc[mi][j] = __builtin_amdgcn_mfma_f32_16x16x32_fp8_fp8(
              af[mi], bfr[j], acc[mi][j], 0, 0, 0);
    }
  };

  stage(0, LA0, LB0);

  constexpr int NKB = KTOT / 64;
  static_assert(NKB % 2 == 0, "K-loop unroll-2 requires even NKB");
#pragma unroll 1
  for (int kbp = 0; kbp < NKB / 2; ++kbp) {
    const int kb0 = kbp * 2;
    // copy A: read buffer 0, prefetch kb0+1 into buffer 1
    __syncthreads();                      // drains stage(kb0)
    stage(kb0 + 1, LA1, LB1);             // kb0+1 <= NKB-1 always
    {
      const bool A16 = GATHER && (kb0 * 64) < K1;
      compute(LA0, LB0, A16 ? ko16_0 : ko8_0, A16 ? ko16_1 : ko8_1);
    }
    // copy B: read buffer 1, prefetch kb0+2 into buffer 0
    __syncthreads();                      // drains stage(kb0+1)
    if (kb0 + 2 < NKB) stage(kb0 + 2, LA0, LB0);
    {
      const bool A16 = GATHER && ((kb0 + 1) * 64) < K1;
      compute(LA1, LB1, A16 ? ko16_0 : ko8_0, A16 ? ko16_1 : ko8_1);
    }
  }

  // epilogue: per-lane holds z_i, z_f, z_g, z_o (j = gate) for unit u.
  // h column swizzle is 8B-granule: f(m) = (m>>1)&7 = qd*2 + (r>>1).
  const int u = n0 / 4 + wn * 16 + cl;     // n0/4 = bn*32
  const int uhi = u & ~63;
  const int uc8 = (u >> 3) & 7;
  const int ulo = u & 7;
  const float bi = bias[u];
  const float bff = bias[1024 + u];
  const float bg = bias[2048 + u];
  const float bo = bias[3072 + u];
#pragma unroll
  for (int mi = 0; mi < 2; ++mi) {
    int mbase = m0 + wm * 32 + mi * 16 + qd * 4;
#pragma unroll
    for (int r = 0; r < 4; ++r) {
      int m = mbase + r;
      int fm = (qd * 2 + (r >> 1)) & 7;
      int hcol = uhi | ((uc8 ^ fm) << 3) | ulo;
      float gi = sigmoidf_(acc[mi][0][r] * SCALE_DN + bi);
      float gf = sigmoidf_(acc[mi][1][r] * SCALE_DN + bff);
      float gg = tanhf_(acc[mi][2][r] * SCALE_DN + bg);
      float go = sigmoidf_(acc[mi][3][r] * SCALE_DN + bo);
      size_t coff = (size_t)m * 1024 + u;
      float cn = gf * cbuf[coff] + gi * gg;
      cbuf[coff] = cn;
      hout[(size_t)m * 1024 + hcol] = f2fp8(go * tanhf_(cn) * SCALE_UP);
    }
  }
}

// mode 0: L0 only (t=0). mode 1: L0(t) then L1(t-1) in every block — all 1024
// blocks identical work (50 K-steps), placement-independent balance.
// mode 2: L1 only (final). Grid always 1024, 64x128 tiles (32 m x 32 n).
__global__ __launch_bounds__(256, 4) void k_step(
    int mode,
    const unsigned char* embp, const unsigned char* h0in,
    const int* idx, int t,
    const unsigned char* WT0, const float* b0, float* c0, unsigned char* h0out,
    const unsigned char* h0prev, const unsigned char* h1in,
    const unsigned char* WT1, const float* b1, float* c1, unsigned char* h1out)
{
  extern __shared__ char smem[];
  const int blk = blockIdx.x;
  const int m0 = (blk >> 5) * 64;
  const int n0 = (blk & 31) * 128;
  if (mode != 2)
    lstm_phase<128, 1152, true>(m0, n0, smem, embp, h0in, idx, t,
                                WT0, b0, c0, h0out);
  if (mode != 0)
    lstm_phase<1024, 2048, false>(m0, n0, smem, h0prev, h1in, nullptr, 0,
                                  WT1, b1, c1, h1out);
}

// ---------------- final FC + sigmoid ----------------

__global__ void k_fc(const unsigned char* __restrict__ h1,
                     const float* __restrict__ fcW, const float* __restrict__ fcb,
                     float* __restrict__ out) {
  int wv = threadIdx.x >> 6;
  int lane = threadIdx.x & 63;
  int row = blockIdx.x * 4 + wv;
  if (row >= 2048) return;
  const unsigned char* hr = h1 + (size_t)row * 1024;
  const int f = (row >> 1) & 7;
  float s = 0.f;
  for (int k = lane; k < 1024; k += 64) {
    int ks = (k & ~63) | ((((k >> 3) & 7) ^ f) << 3) | (k & 7);
    s += fp82f(hr[ks]) * fcW[k];
  }
#pragma unroll
  for (int off = 32; off > 0; off >>= 1) s += __shfl_down(s, off);
  if (lane == 0) out[row] = sigmoidf_(s * (1.0f / SCALE_UP) + fcb[0]);
}

// ---------------- launcher ----------------

extern "C" void kernel_launch(void* const* d_in, const int* in_sizes, int n_in,
                              void* d_out, int out_size, void* d_ws, size_t ws_size,
                              hipStream_t stream) {
  const int*   idx = (const int*)d_in[0];
  const float* emb = (const float*)d_in[1];
  const float* W0  = (const float*)d_in[2];
  const float* U0  = (const float*)d_in[3];
  const float* b0  = (const float*)d_in[4];
  const float* W1  = (const float*)d_in[5];
  const float* U1  = (const float*)d_in[6];
  const float* b1  = (const float*)d_in[7];
  const float* fcW = (const float*)d_in[8];
  const float* fcb = (const float*)d_in[9];
  float* out = (float*)d_out;

  char* ws = (char*)d_ws;
  unsigned char* embp = (unsigned char*)(ws);                   //  1,280,000
  unsigned char* WT0  = (unsigned char*)(ws + 1280000);         //  4,718,592
  unsigned char* WT1  = (unsigned char*)(ws + 5998592);         //  8,388,608
  unsigned char* h0b[2] = {(unsigned char*)(ws + 14387200),
                           (unsigned char*)(ws + 16484352)};    // 2x 2,097,152
  unsigned char* h1b[2] = {(unsigned char*)(ws + 18581504),
                           (unsigned char*)(ws + 20678656)};    // 2x 2,097,152
  float* c0 = (float*)(ws + 22775808);                          //  8,388,608
  float* c1 = (float*)(ws + 31164416);                          //  8,388,608
  // total: 39,553,024 bytes

  // zero h (4 buffers) and c0/c1 — contiguous region
  hipMemsetAsync(ws + 14387200, 0, 25165824, stream);

  k_conv_emb<<<5000, 256, 0, stream>>>(emb, embp);
  k_conv_w0<<<18432, 256, 0, stream>>>(W0, U0, WT0);
  k_conv_w1<<<32768, 256, 0, stream>>>(W1, U1, WT1);

  // t = 0: layer-0 only
  k_step<<<1024, 256, 24576, stream>>>(0, embp, h0b[1], idx, 0,
                                       WT0, b0, c0, h0b[0],
                                       nullptr, nullptr, WT1, b1, c1, nullptr);
  // t = 1..79: merged [L0(t); L1(t-1)] per block — uniform work
  for (int t = 1; t < 80; ++t) {
    k_step<<<1024, 256, 24576, stream>>>(1, embp, h0b[(t + 1) & 1], idx, t,
                                         WT0, b0, c0, h0b[t & 1],
                                         h0b[(t - 1) & 1], h1b[t & 1],
                                         WT1, b1, c1, h1b[(t + 1) & 1]);
  }
  // final: layer-1 at t=79 (src1 = h0b[1], in h1b[0], out h1b[1])
  k_step<<<1024, 256, 24576, stream>>>(2, nullptr, nullptr, nullptr, 0,
                                       WT0, b0, c0, nullptr,
                                       h0b[1], h1b[0], WT1, b1, c1, h1b[1]);

  k_fc<<<512, 256, 0, stream>>>(h1b[1], fcW, fcb, out);
}

// Round 11
// 3796.580 us; speedup vs baseline: 1.1315x; 1.1315x over previous
//
#include <hip/hip_runtime.h>

#define DEVI __device__ __forceinline__

typedef __attribute__((ext_vector_type(4))) float f4;
typedef long long i64t;

DEVI unsigned char f2fp8(float x) {
  int p = __builtin_amdgcn_cvt_pk_fp8_f32(x, x, 0, false);
  return (unsigned char)(p & 0xff);
}
DEVI float fp82f(unsigned char b) {
  return __builtin_amdgcn_cvt_f32_fp8((int)b, 0);
}
DEVI float sigmoidf_(float x) { return 1.f / (1.f + __expf(-x)); }
DEVI float tanhf_(float x) {
  float ax = fabsf(x);
  float e = __expf(-2.f * ax);
  float t = (1.f - e) / (1.f + e);
  return x < 0.f ? -t : t;
}

#define GLDS16(g, l) __builtin_amdgcn_global_load_lds( \
    (const __attribute__((address_space(1))) void*)(g), \
    (__attribute__((address_space(3))) void*)(l), 16, 0, 0)

// All GEMM operands are fp8 e4m3 scaled by 64 (raw values ~N(0,0.02) are
// subnormal in e4m3; x64 centers them in the normal range). acc = 4096*z;
// epilogue multiplies by 1/4096.
#define SCALE_UP 64.0f
#define SCALE_DN (1.0f / 4096.0f)

// ---------------- conversion kernels ----------------

__global__ void k_conv_emb(const float* __restrict__ emb, unsigned char* __restrict__ ep) {
  int i = blockIdx.x * 256 + threadIdx.x;            // 10000 * 128
  if (i >= 10000 * 128) return;
  int r = i >> 7, c = i & 127;
  ep[i] = (c < 100) ? f2fp8(emb[r * 100 + c] * SCALE_UP) : (unsigned char)0;
}

// column permutation: original col n = gate*1024 + u  ->
// n' = (u/32)*128 + ((u%32)/16)*64 + gate*16 + (u%16)
DEVI int permn(int n) {
  int g = n >> 10, u = n & 1023;
  return (u >> 5) * 128 + ((u >> 4) & 1) * 64 + g * 16 + (u & 15);
}
// bank swizzle baked into storage, 8-BYTE granule: within each 64B k-block,
// 8B slot s of row r holds logical slot s ^ ((r>>1)&7). This gives each
// quarter-wave (16 lanes, the LDS coalescing window) all 32 banks exactly
// once on ds_read_b64. (Verified round 2: SQ_LDS_BANK_CONFLICT 6.55M -> 65K.)
DEVI int kswz(int klog, int row) {
  return (klog & ~63) | (((((klog >> 3) & 7) ^ ((row >> 1) & 7))) << 3) | (klog & 7);
}

__global__ void k_conv_w0(const float* __restrict__ W0, const float* __restrict__ U0,
                          unsigned char* __restrict__ WT) {
  int i = blockIdx.x * 256 + threadIdx.x;            // 4096 * 1152
  if (i >= 4096 * 1152) return;
  int n = i / 1152, k = i - n * 1152;
  float v;
  if (k < 100) v = W0[k * 4096 + n];
  else if (k < 128) v = 0.f;
  else v = U0[(k - 128) * 4096 + n];
  int np = permn(n);
  WT[(size_t)np * 1152 + kswz(k, np)] = f2fp8(v * SCALE_UP);
}

__global__ void k_conv_w1(const float* __restrict__ W1, const float* __restrict__ U1,
                          unsigned char* __restrict__ WT) {
  int i = blockIdx.x * 256 + threadIdx.x;            // 4096 * 2048
  if (i >= 4096 * 2048) return;
  int n = i >> 11, k = i & 2047;
  float v = (k < 1024) ? W1[k * 4096 + n] : U1[(k - 1024) * 4096 + n];
  int np = permn(n);
  WT[(size_t)np * 2048 + kswz(k, np)] = f2fp8(v * SCALE_UP);
}

// ---------------- fused LSTM phase (fp8) ------------------------------------
// Round 11: COUNTED-VMCNT 4-DEEP PIPELINE on the round-9 geometry (its 64x128
// variant regressed; 128x128/8-wave restored). Rationale: FETCH ~= whole
// working set per step -> stage loads are HBM-latency (~900cy); the 2-phase
// __syncthreads drain left only ~600-1200cy slack (marginal). Now loads are
// issued 3 K-blocks ahead (4-buffer static ring, 64KB LDS) and the wait is
// a counted vmcnt(4) (tail: 2 then 0) + builtin s_barrier -- never a full
// drain mid-loop. K-loop FULLY UNROLLED (NKB is a template constant) so all
// ring-buffer bindings constant-fold (round-2's failure: runtime-indexed
// buffers -> scratch/cndmask + opaque asm barrier + setprio; all avoided).
// Safety: vmcnt retires in-order, so older epilogue/prologue vector ops only
// make the counted wait stricter; stage(kb+3) overwrites the buffer of kb-1
// only after a barrier at which every wave's kb-1 reads have completed (its
// MFMAs consumed them); __syncthreads at the L0->L1 splice (in k_step)
// protects the next phase's prologue staging.
// MERGED-BLOCK: every block runs L0(t) (18 kb) then L1(t-1) (32 kb) on the
// same 128 m-rows -- uniform work, no placement assumptions.
// h and WT storage carry the 8B-granule bank swizzle; gathered embp XORs at
// stage time (16B granule, kb<2 of L0 only, read back with 16B offsets).
// c-state fp32 (bf16 r6/r7 gave no per-dispatch gain).

template<int K1, int KTOT, bool GATHER>
DEVI void lstm_phase(int m0, int n0, char* smem,
    const unsigned char* __restrict__ src1,   // embp (gathered) or h0(t-1)
    const unsigned char* __restrict__ src2,   // h prev (recurrent input)
    const int* __restrict__ idx, int t,
    const unsigned char* __restrict__ WT,     // [4096][KTOT] fp8, perm+swz
    const float* __restrict__ bias,           // [4096] original layout
    float* __restrict__ cbuf,                 // [2048][1024] fp32, in-place
    unsigned char* __restrict__ hout)         // [2048][1024] fp8 x64, swz
{
  const int tid = threadIdx.x;               // 0..511

  const int lr = tid >> 2;                 // staging row 0..127
  const int c16 = (tid & 3) * 16;          // plain 16B chunk offset
  // stage-time 16B XOR for gathered embp: dest chunk (tid&3) at LDS row lr
  // holds logical chunk (tid&3) ^ ((lr>>1)&3)
  const int csw = (((tid & 3) ^ ((tid >> 3) & 3))) * 16;

  const unsigned char* g1 = nullptr;       // gathered embp row (pre-offset)
  if (GATHER) {
    int w = idx[(m0 + lr) * 80 + t];
    g1 = src1 + (size_t)w * K1 + csw;
  }

  // hoisted staging base pointers (advance by kc only)
  const unsigned char* wbase = WT + (size_t)(n0 + lr) * KTOT + c16;
  const unsigned char* a1b = src1 + (size_t)(m0 + lr) * 1024 + c16;  // !GATHER
  const unsigned char* a2b = src2 + (size_t)(m0 + lr) * 1024 + c16 - K1;

  // 4-deep ring: each 16KB = A[128][64] (8KB) + B[128][64] (8KB)
  char* const SAs[4] = {smem, smem + 16384, smem + 32768, smem + 49152};

  auto stage = [&](int kb, char* la) {
    char* lb = la + 8192;
    const int kc = kb * 64;
    if (GATHER && kc < K1) {
      GLDS16(g1 + kc, la + tid * 16);
    } else {
      const unsigned char* g = (!GATHER && kc < K1) ? a1b + kc : a2b + kc;
      GLDS16(g, la + tid * 16);
    }
    GLDS16(wbase + kc, lb + tid * 16);     // 2 loads/thread/stage (vmcnt math)
  };

  const int lane = tid & 63;
  const int wv = tid >> 6;    // 0..7
  const int wm = wv >> 1;     // wave m-quarter (0..3), 32 rows each
  const int wn = wv & 1;      // wave n-half (0..1), 64 n'-rows each
  const int cl = lane & 15;
  const int qd = lane >> 4;
  const int qh = qd >> 1, qb = qd & 1;
  // 8B-granule swizzled fragment byte-offsets (baked storage):
  // logical 8B slot for (kk,qd) = kk*4 + qd; phys = slot ^ ((cl>>1)&7)
  const int g8s = (cl >> 1) & 7;
  const int ko8_0 = ((0 + qd) ^ g8s) << 3;
  const int ko8_1 = ((4 + qd) ^ g8s) << 3;
  // 16B-granule offsets (embp-gathered A tiles only, kb<2 of layer 0)
  const int g4s = (cl >> 1) & 3;
  const int ko16_0 = ((qh ^ g4s) << 4) + qb * 8;
  const int ko16_1 = (((2 + qh) ^ g4s) << 4) + qb * 8;

  f4 acc[2][4];
  const f4 fz = {0.f, 0.f, 0.f, 0.f};
#pragma unroll
  for (int a = 0; a < 2; ++a)
#pragma unroll
    for (int b = 0; b < 4; ++b) acc[a][b] = fz;

  auto compute = [&](char* la, int koA0, int koA1) {
    char* lb = la + 8192;
#pragma unroll
    for (int kk = 0; kk < 2; ++kk) {
      const int koA = kk ? koA1 : koA0;
      const int koB = kk ? ko8_1 : ko8_0;
      i64t af[2], bfr[4];
#pragma unroll
      for (int mi = 0; mi < 2; ++mi)
        af[mi] = *(const i64t*)(la + (wm * 32 + mi * 16 + cl) * 64 + koA);
#pragma unroll
      for (int j = 0; j < 4; ++j)
        bfr[j] = *(const i64t*)(lb + (wn * 64 + j * 16 + cl) * 64 + koB);
#pragma unroll
      for (int mi = 0; mi < 2; ++mi)
#pragma unroll
        for (int j = 0; j < 4; ++j)
          acc[mi][j] = __builtin_amdgcn_mfma_f32_16x16x32_fp8_fp8(
              af[mi], bfr[j], acc[mi][j], 0, 0, 0);
    }
  };

  // prologue: 3 stages in flight before first compute
  stage(0, SAs[0]);
  stage(1, SAs[1]);
  stage(2, SAs[2]);

  constexpr int NKB = KTOT / 64;
  // fully unrolled: kb is compile-time in every copy -> static ring binding,
  // static wait selection, static stage guards.
#pragma unroll
  for (int kb = 0; kb < NKB; ++kb) {
    if (kb < NKB - 2)
      asm volatile("s_waitcnt vmcnt(4)" ::: "memory");   // kb done; kb+1,kb+2 fly
    else if (kb == NKB - 2)
      asm volatile("s_waitcnt vmcnt(2)" ::: "memory");
    else
      asm volatile("s_waitcnt vmcnt(0)" ::: "memory");
    __builtin_amdgcn_s_barrier();
    if (kb + 3 < NKB) stage(kb + 3, SAs[(kb + 3) & 3]);
    const bool A16 = GATHER && (kb * 64) < K1;
    compute(SAs[kb & 3], A16 ? ko16_0 : ko8_0, A16 ? ko16_1 : ko8_1);
  }

  // epilogue: per-lane holds z_i, z_f, z_g, z_o (j = gate) for unit u.
  // h column swizzle is 8B-granule: f(m) = (m>>1)&7 = qd*2 + (r>>1).
  const int u = n0 / 4 + wn * 16 + cl;     // n0/4 = bn*32
  const int uhi = u & ~63;
  const int uc8 = (u >> 3) & 7;
  const int ulo = u & 7;
  const float bi = bias[u];
  const float bff = bias[1024 + u];
  const float bg = bias[2048 + u];
  const float bo = bias[3072 + u];
#pragma unroll
  for (int mi = 0; mi < 2; ++mi) {
    int mbase = m0 + wm * 32 + mi * 16 + qd * 4;
#pragma unroll
    for (int r = 0; r < 4; ++r) {
      int m = mbase + r;
      int fm = (qd * 2 + (r >> 1)) & 7;
      int hcol = uhi | ((uc8 ^ fm) << 3) | ulo;
      float gi = sigmoidf_(acc[mi][0][r] * SCALE_DN + bi);
      float gf = sigmoidf_(acc[mi][1][r] * SCALE_DN + bff);
      float gg = tanhf_(acc[mi][2][r] * SCALE_DN + bg);
      float go = sigmoidf_(acc[mi][3][r] * SCALE_DN + bo);
      size_t coff = (size_t)m * 1024 + u;
      float cn = gf * cbuf[coff] + gi * gg;
      cbuf[coff] = cn;
      hout[(size_t)m * 1024 + hcol] = f2fp8(go * tanhf_(cn) * SCALE_UP);
    }
  }
}

// mode 0: L0 only (t=0). mode 1: L0(t) then L1(t-1) in every block — all 512
// blocks identical work (50 K-steps), placement-independent balance.
// mode 2: L1 only (final). Grid always 512, 128x128 tiles (16 m x 32 n).
__global__ __launch_bounds__(512, 4) void k_step(
    int mode,
    const unsigned char* embp, const unsigned char* h0in,
    const int* idx, int t,
    const unsigned char* WT0, const float* b0, float* c0, unsigned char* h0out,
    const unsigned char* h0prev, const unsigned char* h1in,
    const unsigned char* WT1, const float* b1, float* c1, unsigned char* h1out)
{
  extern __shared__ char smem[];
  const int blk = blockIdx.x;
  const int m0 = (blk >> 5) * 128;
  const int n0 = (blk & 31) * 128;
  if (mode != 2)
    lstm_phase<128, 1152, true>(m0, n0, smem, embp, h0in, idx, t,
                                WT0, b0, c0, h0out);
  if (mode == 1)
    __syncthreads();   // protect L1 prologue staging vs L0 tail LDS reads
  if (mode != 0)
    lstm_phase<1024, 2048, false>(m0, n0, smem, h0prev, h1in, nullptr, 0,
                                  WT1, b1, c1, h1out);
}

// ---------------- final FC + sigmoid ----------------

__global__ void k_fc(const unsigned char* __restrict__ h1,
                     const float* __restrict__ fcW, const float* __restrict__ fcb,
                     float* __restrict__ out) {
  int wv = threadIdx.x >> 6;
  int lane = threadIdx.x & 63;
  int row = blockIdx.x * 4 + wv;
  if (row >= 2048) return;
  const unsigned char* hr = h1 + (size_t)row * 1024;
  const int f = (row >> 1) & 7;
  float s = 0.f;
  for (int k = lane; k < 1024; k += 64) {
    int ks = (k & ~63) | ((((k >> 3) & 7) ^ f) << 3) | (k & 7);
    s += fp82f(hr[ks]) * fcW[k];
  }
#pragma unroll
  for (int off = 32; off > 0; off >>= 1) s += __shfl_down(s, off);
  if (lane == 0) out[row] = sigmoidf_(s * (1.0f / SCALE_UP) + fcb[0]);
}

// ---------------- launcher ----------------

extern "C" void kernel_launch(void* const* d_in, const int* in_sizes, int n_in,
                              void* d_out, int out_size, void* d_ws, size_t ws_size,
                              hipStream_t stream) {
  const int*   idx = (const int*)d_in[0];
  const float* emb = (const float*)d_in[1];
  const float* W0  = (const float*)d_in[2];
  const float* U0  = (const float*)d_in[3];
  const float* b0  = (const float*)d_in[4];
  const float* W1  = (const float*)d_in[5];
  const float* U1  = (const float*)d_in[6];
  const float* b1  = (const float*)d_in[7];
  const float* fcW = (const float*)d_in[8];
  const float* fcb = (const float*)d_in[9];
  float* out = (float*)d_out;

  char* ws = (char*)d_ws;
  unsigned char* embp = (unsigned char*)(ws);                   //  1,280,000
  unsigned char* WT0  = (unsigned char*)(ws + 1280000);         //  4,718,592
  unsigned char* WT1  = (unsigned char*)(ws + 5998592);         //  8,388,608
  unsigned char* h0b[2] = {(unsigned char*)(ws + 14387200),
                           (unsigned char*)(ws + 16484352)};    // 2x 2,097,152
  unsigned char* h1b[2] = {(unsigned char*)(ws + 18581504),
                           (unsigned char*)(ws + 20678656)};    // 2x 2,097,152
  float* c0 = (float*)(ws + 22775808);                          //  8,388,608
  float* c1 = (float*)(ws + 31164416);                          //  8,388,608
  // total: 39,553,024 bytes

  // zero h (4 buffers) and c0/c1 — contiguous region
  hipMemsetAsync(ws + 14387200, 0, 25165824, stream);

  k_conv_emb<<<5000, 256, 0, stream>>>(emb, embp);
  k_conv_w0<<<18432, 256, 0, stream>>>(W0, U0, WT0);
  k_conv_w1<<<32768, 256, 0, stream>>>(W1, U1, WT1);

  // t = 0: layer-0 only
  k_step<<<512, 512, 65536, stream>>>(0, embp, h0b[1], idx, 0,
                                      WT0, b0, c0, h0b[0],
                                      nullptr, nullptr, WT1, b1, c1, nullptr);
  // t = 1..79: merged [L0(t); L1(t-1)] per block — uniform work
  for (int t = 1; t < 80; ++t) {
    k_step<<<512, 512, 65536, stream>>>(1, embp, h0b[(t + 1) & 1], idx, t,
                                        WT0, b0, c0, h0b[t & 1],
                                        h0b[(t - 1) & 1], h1b[t & 1],
                                        WT1, b1, c1, h1b[(t + 1) & 1]);
  }
  // final: layer-1 at t=79 (src1 = h0b[1], in h1b[0], out h1b[1])
  k_step<<<512, 512, 65536, stream>>>(2, nullptr, nullptr, nullptr, 0,
                                      WT0, b0, c0, nullptr,
                                      h0b[1], h1b[0], WT1, b1, c1, h1b[1]);

  k_fc<<<512, 256, 0, stream>>>(h1b[1], fcW, fcb, out);
}

// Round 12
// 3568.954 us; speedup vs baseline: 1.2037x; 1.0638x over previous
//
#include <hip/hip_runtime.h>

#define DEVI __device__ __forceinline__

typedef __attribute__((ext_vector_type(4))) float f4;
typedef long long i64t;

DEVI unsigned char f2fp8(float x) {
  int p = __builtin_amdgcn_cvt_pk_fp8_f32(x, x, 0, false);
  return (unsigned char)(p & 0xff);
}
DEVI float fp82f(unsigned char b) {
  return __builtin_amdgcn_cvt_f32_fp8((int)b, 0);
}
DEVI float sigmoidf_(float x) { return 1.f / (1.f + __expf(-x)); }
DEVI float tanhf_(float x) {
  float ax = fabsf(x);
  float e = __expf(-2.f * ax);
  float t = (1.f - e) / (1.f + e);
  return x < 0.f ? -t : t;
}

#define GLDS16(g, l) __builtin_amdgcn_global_load_lds( \
    (const __attribute__((address_space(1))) void*)(g), \
    (__attribute__((address_space(3))) void*)(l), 16, 0, 0)

// All GEMM operands are fp8 e4m3 scaled by 64 (raw values ~N(0,0.02) are
// subnormal in e4m3; x64 centers them in the normal range). acc = 4096*z;
// epilogue multiplies by 1/4096.
#define SCALE_UP 64.0f
#define SCALE_DN (1.0f / 4096.0f)

// ---------------- conversion kernels ----------------

__global__ void k_conv_emb(const float* __restrict__ emb, unsigned char* __restrict__ ep) {
  int i = blockIdx.x * 256 + threadIdx.x;            // 10000 * 128
  if (i >= 10000 * 128) return;
  int r = i >> 7, c = i & 127;
  ep[i] = (c < 100) ? f2fp8(emb[r * 100 + c] * SCALE_UP) : (unsigned char)0;
}

// column permutation: original col n = gate*1024 + u  ->
// n' = (u/32)*128 + ((u%32)/16)*64 + gate*16 + (u%16)
DEVI int permn(int n) {
  int g = n >> 10, u = n & 1023;
  return (u >> 5) * 128 + ((u >> 4) & 1) * 64 + g * 16 + (u & 15);
}
// bank swizzle baked into storage, 8-BYTE granule: within each 64B k-block,
// 8B slot s of row r holds logical slot s ^ ((r>>1)&7). This gives each
// quarter-wave (16 lanes, the LDS coalescing window) all 32 banks exactly
// once on ds_read_b64. (Verified round 2: SQ_LDS_BANK_CONFLICT 6.55M -> 65K.)
DEVI int kswz(int klog, int row) {
  return (klog & ~63) | (((((klog >> 3) & 7) ^ ((row >> 1) & 7))) << 3) | (klog & 7);
}

__global__ void k_conv_w0(const float* __restrict__ W0, const float* __restrict__ U0,
                          unsigned char* __restrict__ WT) {
  int i = blockIdx.x * 256 + threadIdx.x;            // 4096 * 1152
  if (i >= 4096 * 1152) return;
  int n = i / 1152, k = i - n * 1152;
  float v;
  if (k < 100) v = W0[k * 4096 + n];
  else if (k < 128) v = 0.f;
  else v = U0[(k - 128) * 4096 + n];
  int np = permn(n);
  WT[(size_t)np * 1152 + kswz(k, np)] = f2fp8(v * SCALE_UP);
}

__global__ void k_conv_w1(const float* __restrict__ W1, const float* __restrict__ U1,
                          unsigned char* __restrict__ WT) {
  int i = blockIdx.x * 256 + threadIdx.x;            // 4096 * 2048
  if (i >= 4096 * 2048) return;
  int n = i >> 11, k = i & 2047;
  float v = (k < 1024) ? W1[k * 4096 + n] : U1[(k - 1024) * 4096 + n];
  int np = permn(n);
  WT[(size_t)np * 2048 + kswz(k, np)] = f2fp8(v * SCALE_UP);
}

// ---------------- fused LSTM step body (fp8) --------------------------------
// Round 12: r3 geometry (256x128 tile, 8 waves as 4M x 2N, per-wave 64x64
// output acc[4][4]) + r11's counted-vmcnt pipeline as a 3-DEEP RING
// (3 x 24KB = 72KB LDS -> 2 blocks/CU). Rationale (r11 post-mortem): LDS
// bandwidth was co-binding — the 32x64 wave reads 384 B of LDS per MFMA
// (131KB per CU K-block-pair ~ 1500cy vs 1241cy of MFMA). The 64x64 wave
// reads 256 B/MFMA (8 ds_read_b64 per 16 MFMA) and doubles MFMA per barrier;
// at the new ratio LDS needs ~73 B/cyc at the MFMA floor — no longer binding.
// Pipeline: fully-unrolled K-loop (static ring binding, r2's runtime-indexed
// failure avoided), counted s_waitcnt vmcnt(3) (stage = 3 GLDS/thread;
// prologue keeps 2 stages in flight; slack = 2 iterations ~ 4800cy >> 900cy
// HBM latency), builtin s_barrier, tail vmcnt(0). Ring-3 reuse: stage(kb+2)
// overwrites kb-1's buffer only after the barrier at which all waves
// finished compute(kb-1) (their ds_reads were consumed by pre-barrier MFMAs).
// Split L0/L1 blocks with the r3-PROVEN balanced type map (34.4 MB fetch).
// h and WT storage carry the 8B-granule bank swizzle; gathered embp XORs at
// stage time (16B granule, kb<2 of L0 only, 16B-granule readback).
// c-state fp32 (bf16 r6/r7 gave no per-dispatch gain).

template<int K1, int KTOT, bool GATHER>
DEVI void lstm_body(int tile, char* smem,
    const unsigned char* __restrict__ src1,   // embp (gathered) or h0(t-1)
    const unsigned char* __restrict__ src2,   // h prev (recurrent input)
    const int* __restrict__ idx, int t,
    const unsigned char* __restrict__ WT,     // [4096][KTOT] fp8, perm+swz
    const float* __restrict__ bias,           // [4096] original layout
    float* __restrict__ cbuf,                 // [2048][1024] fp32, in-place
    unsigned char* __restrict__ hout)         // [2048][1024] fp8 x64, swz
{
  const int tid = threadIdx.x;
  const int bn = tile & 31;
  const int bm = tile >> 5;
  const int m0 = bm * 256;
  const int n0 = bn * 128;

  const int lr = tid >> 2;                 // staging row-in-pass 0..127
  const int c16 = (tid & 3) * 16;          // plain 16B chunk offset
  // stage-time 16B XOR for gathered embp: dest chunk (tid&3) at LDS row lr
  // holds logical chunk (tid&3) ^ ((lr>>1)&3), lr = tid>>2
  const int csw = (((tid & 3) ^ ((tid >> 3) & 3))) * 16;

  const unsigned char* g1[2];              // gathered embp rows (pre-offset)
  if (GATHER) {
#pragma unroll
    for (int p = 0; p < 2; ++p) {
      int w = idx[(m0 + p * 128 + lr) * 80 + t];
      g1[p] = src1 + (size_t)w * K1 + csw;
    }
  }

  // hoisted per-thread staging base pointers (advance by kc only)
  const unsigned char* wbase = WT + (size_t)(n0 + lr) * KTOT + c16;
  const unsigned char* a1b[2];
  const unsigned char* a2b[2];
#pragma unroll
  for (int p = 0; p < 2; ++p) {
    size_t row = (size_t)(m0 + p * 128 + lr);
    a1b[p] = src1 + row * 1024 + c16;            // unused when GATHER
    a2b[p] = src2 + row * 1024 + c16 - K1;       // valid for kc >= K1
  }

  // 3-deep ring: each 24KB = A[256][64] (16KB) + B[128][64] (8KB)
  char* const SAs[3] = {smem, smem + 24576, smem + 49152};

  auto stage = [&](int kb, char* la) {
    char* lb = la + 16384;
    const int kc = kb * 64;
    if (GATHER && kc < K1) {
#pragma unroll
      for (int p = 0; p < 2; ++p)
        GLDS16(g1[p] + kc, la + p * 8192 + tid * 16);
    } else {
#pragma unroll
      for (int p = 0; p < 2; ++p) {
        const unsigned char* g = (!GATHER && kc < K1) ? a1b[p] + kc
                                                      : a2b[p] + kc;
        GLDS16(g, la + p * 8192 + tid * 16);
      }
    }
    GLDS16(wbase + kc, lb + tid * 16);   // 3 GLDS/thread/stage (vmcnt math)
  };

  const int lane = tid & 63;
  const int wv = tid >> 6;    // 0..7
  const int wm = wv >> 1;     // wave m-quarter (0..3), 64 rows each
  const int wn = wv & 1;      // wave n-half (0..1), 64 n'-rows each
  const int cl = lane & 15;
  const int qd = lane >> 4;
  const int qh = qd >> 1, qb = qd & 1;
  // 8B-granule swizzled fragment byte-offsets (baked storage):
  // logical 8B slot for (kk,qd) = kk*4 + qd; phys = slot ^ ((cl>>1)&7)
  const int g8s = (cl >> 1) & 7;
  const int ko8_0 = ((0 + qd) ^ g8s) << 3;
  const int ko8_1 = ((4 + qd) ^ g8s) << 3;
  // 16B-granule offsets (embp-gathered A tiles only, kb<2 of layer 0)
  const int g4s = (cl >> 1) & 3;
  const int ko16_0 = ((qh ^ g4s) << 4) + qb * 8;
  const int ko16_1 = (((2 + qh) ^ g4s) << 4) + qb * 8;

  f4 acc[4][4];
  const f4 fz = {0.f, 0.f, 0.f, 0.f};
#pragma unroll
  for (int a = 0; a < 4; ++a)
#pragma unroll
    for (int b = 0; b < 4; ++b) acc[a][b] = fz;

  auto compute = [&](char* la, int koA0, int koA1) {
    char* lb = la + 16384;
#pragma unroll
    for (int kk = 0; kk < 2; ++kk) {
      const int koA = kk ? koA1 : koA0;
      const int koB = kk ? ko8_1 : ko8_0;
      i64t af[4], bfr[4];
#pragma unroll
      for (int mi = 0; mi < 4; ++mi)
        af[mi] = *(const i64t*)(la + (wm * 64 + mi * 16 + cl) * 64 + koA);
#pragma unroll
      for (int j = 0; j < 4; ++j)
        bfr[j] = *(const i64t*)(lb + (wn * 64 + j * 16 + cl) * 64 + koB);
#pragma unroll
      for (int mi = 0; mi < 4; ++mi)
#pragma unroll
        for (int j = 0; j < 4; ++j)
          acc[mi][j] = __builtin_amdgcn_mfma_f32_16x16x32_fp8_fp8(
              af[mi], bfr[j], acc[mi][j], 0, 0, 0);
    }
  };

  // prologue: 2 stages in flight before first compute
  stage(0, SAs[0]);
  stage(1, SAs[1]);

  constexpr int NKB = KTOT / 64;
  // fully unrolled: kb compile-time in every copy -> static ring binding,
  // static wait selection, static stage guards.
#pragma unroll
  for (int kb = 0; kb < NKB; ++kb) {
    if (kb < NKB - 1)
      asm volatile("s_waitcnt vmcnt(3)" ::: "memory");  // kb done; kb+1 flies
    else
      asm volatile("s_waitcnt vmcnt(0)" ::: "memory");
    __builtin_amdgcn_s_barrier();
    if (kb + 2 < NKB) stage(kb + 2, SAs[(kb + 2) % 3]);
    const bool A16 = GATHER && (kb * 64) < K1;
    compute(SAs[kb % 3], A16 ? ko16_0 : ko8_0, A16 ? ko16_1 : ko8_1);
  }

  // epilogue: per-lane holds z_i, z_f, z_g, z_o (j = gate) for unit u.
  // h column swizzle is 8B-granule: f(m) = (m>>1)&7 = qd*2 + (r>>1).
  const int u = bn * 32 + wn * 16 + cl;
  const int uhi = u & ~63;
  const int uc8 = (u >> 3) & 7;
  const int ulo = u & 7;
  const float bi = bias[u];
  const float bff = bias[1024 + u];
  const float bg = bias[2048 + u];
  const float bo = bias[3072 + u];
#pragma unroll
  for (int mi = 0; mi < 4; ++mi) {
    int mbase = m0 + wm * 64 + mi * 16 + qd * 4;
#pragma unroll
    for (int r = 0; r < 4; ++r) {
      int m = mbase + r;
      int fm = (qd * 2 + (r >> 1)) & 7;
      int hcol = uhi | ((uc8 ^ fm) << 3) | ulo;
      float gi = sigmoidf_(acc[mi][0][r] * SCALE_DN + bi);
      float gf = sigmoidf_(acc[mi][1][r] * SCALE_DN + bff);
      float gg = tanhf_(acc[mi][2][r] * SCALE_DN + bg);
      float go = sigmoidf_(acc[mi][3][r] * SCALE_DN + bo);
      size_t coff = (size_t)m * 1024 + u;
      float cn = gf * cbuf[coff] + gi * gg;
      cbuf[coff] = cn;
      hout[(size_t)m * 1024 + hcol] = f2fp8(go * tanhf_(cn) * SCALE_UP);
    }
  }
}

// mode 0: layer-0 only (grid 256). mode 1: fused (grid 512), with the
// round-3-PROVEN type map (34.4 MB fetch/step measured): type(b) =
// (b&1) ^ ((b>>8)&1) alternates within consecutive pairs {2c,2c+1} AND
// within wrap pairs {c, c+256} -> every CU gets one L1 + one L0 block.
// mode 2: layer-1 only (grid 256).
__global__ __launch_bounds__(512, 4) void k_step(
    int mode,
    const unsigned char* embp, const unsigned char* h0in,
    const int* idx, int t,
    const unsigned char* WT0, const float* b0, float* c0, unsigned char* h0out,
    const unsigned char* h0prev, const unsigned char* h1in,
    const unsigned char* WT1, const float* b1, float* c1, unsigned char* h1out)
{
  extern __shared__ char smem[];
  const int blk = blockIdx.x;
  int tile;
  bool isL0;
  if (mode == 1) {
    int hi = (blk >> 8) & 1;
    isL0 = ((blk & 1) ^ hi) != 0;
    tile = hi * 128 + ((blk & 255) >> 1);
  } else {
    tile = blk;
    isL0 = (mode == 0);
  }
  if (isL0)
    lstm_body<128, 1152, true>(tile, smem, embp, h0in, idx, t,
                               WT0, b0, c0, h0out);
  else
    lstm_body<1024, 2048, false>(tile, smem, h0prev, h1in, nullptr, 0,
                                 WT1, b1, c1, h1out);
}

// ---------------- final FC + sigmoid ----------------

__global__ void k_fc(const unsigned char* __restrict__ h1,
                     const float* __restrict__ fcW, const float* __restrict__ fcb,
                     float* __restrict__ out) {
  int wv = threadIdx.x >> 6;
  int lane = threadIdx.x & 63;
  int row = blockIdx.x * 4 + wv;
  if (row >= 2048) return;
  const unsigned char* hr = h1 + (size_t)row * 1024;
  const int f = (row >> 1) & 7;
  float s = 0.f;
  for (int k = lane; k < 1024; k += 64) {
    int ks = (k & ~63) | ((((k >> 3) & 7) ^ f) << 3) | (k & 7);
    s += fp82f(hr[ks]) * fcW[k];
  }
#pragma unroll
  for (int off = 32; off > 0; off >>= 1) s += __shfl_down(s, off);
  if (lane == 0) out[row] = sigmoidf_(s * (1.0f / SCALE_UP) + fcb[0]);
}

// ---------------- launcher ----------------

extern "C" void kernel_launch(void* const* d_in, const int* in_sizes, int n_in,
                              void* d_out, int out_size, void* d_ws, size_t ws_size,
                              hipStream_t stream) {
  const int*   idx = (const int*)d_in[0];
  const float* emb = (const float*)d_in[1];
  const float* W0  = (const float*)d_in[2];
  const float* U0  = (const float*)d_in[3];
  const float* b0  = (const float*)d_in[4];
  const float* W1  = (const float*)d_in[5];
  const float* U1  = (const float*)d_in[6];
  const float* b1  = (const float*)d_in[7];
  const float* fcW = (const float*)d_in[8];
  const float* fcb = (const float*)d_in[9];
  float* out = (float*)d_out;

  char* ws = (char*)d_ws;
  unsigned char* embp = (unsigned char*)(ws);                   //  1,280,000
  unsigned char* WT0  = (unsigned char*)(ws + 1280000);         //  4,718,592
  unsigned char* WT1  = (unsigned char*)(ws + 5998592);         //  8,388,608
  unsigned char* h0b[2] = {(unsigned char*)(ws + 14387200),
                           (unsigned char*)(ws + 16484352)};    // 2x 2,097,152
  unsigned char* h1b[2] = {(unsigned char*)(ws + 18581504),
                           (unsigned char*)(ws + 20678656)};    // 2x 2,097,152
  float* c0 = (float*)(ws + 22775808);                          //  8,388,608
  float* c1 = (float*)(ws + 31164416);                          //  8,388,608
  // total: 39,553,024 bytes

  // zero h (4 buffers) and c0/c1 — contiguous region
  hipMemsetAsync(ws + 14387200, 0, 25165824, stream);

  k_conv_emb<<<5000, 256, 0, stream>>>(emb, embp);
  k_conv_w0<<<18432, 256, 0, stream>>>(W0, U0, WT0);
  k_conv_w1<<<32768, 256, 0, stream>>>(W1, U1, WT1);

  // t = 0: layer-0 only
  k_step<<<256, 512, 73728, stream>>>(0, embp, h0b[1], idx, 0,
                                      WT0, b0, c0, h0b[0],
                                      nullptr, nullptr, WT1, b1, c1, nullptr);
  // t = 1..79: fused [layer-1(t-1) | layer-0(t)], balanced type map
  for (int t = 1; t < 80; ++t) {
    k_step<<<512, 512, 73728, stream>>>(1, embp, h0b[(t + 1) & 1], idx, t,
                                        WT0, b0, c0, h0b[t & 1],
                                        h0b[(t - 1) & 1], h1b[t & 1],
                                        WT1, b1, c1, h1b[(t + 1) & 1]);
  }
  // final: layer-1 at t=79 (src1 = h0b[1], in h1b[0], out h1b[1])
  k_step<<<256, 512, 73728, stream>>>(2, nullptr, nullptr, nullptr, 0,
                                      WT0, b0, c0, nullptr,
                                      h0b[1], h1b[0], WT1, b1, c1, h1b[1]);

  k_fc<<<512, 256, 0, stream>>>(h1b[1], fcW, fcb, out);
}